// Round 1
// baseline (1100.940 us; speedup 1.0000x reference)
//
#include <hip/hip_runtime.h>
#include <float.h>
#include <math.h>

// Problem constants (fixed by reference): query (8,512,64,64) f32, keys (2000,512) f32
constexpr int B_  = 8;
constexpr int D_  = 512;
constexpr int HW_ = 4096;           // 64*64
constexpr int N_  = 32768;          // B*HW
constexpr int M_  = 2000;
constexpr int MP_ = 2048;           // padded key count

// ---------------- kernel 1: per-pixel reciprocal norms ----------------
// block: 256 thr = (64 pixels) x (4 c-chunks); block covers 128 pixels.
__global__ __launch_bounds__(256) void k_rnorm(const float* __restrict__ q,
                                               float* __restrict__ rnorm) {
    __shared__ float part[128][5];
    int t = threadIdx.x;
    int pl = t & 63, cg = t >> 6;
    int p0 = blockIdx.x * 128;                       // 128 | 4096 -> single batch per block
    const float* base = q + (size_t)(p0 / HW_) * (D_ * HW_) + (p0 % HW_);
    float s0 = 0.f, s1 = 0.f;
    int cbeg = cg * 128;
    for (int c = cbeg; c < cbeg + 128; ++c) {
        float v0 = base[(size_t)c * HW_ + pl];       // coalesced along hw
        float v1 = base[(size_t)c * HW_ + 64 + pl];
        s0 += v0 * v0;
        s1 += v1 * v1;
    }
    part[pl][cg] = s0;
    part[pl + 64][cg] = s1;
    __syncthreads();
    if (t < 128) {
        float s = part[t][0] + part[t][1] + part[t][2] + part[t][3];
        rnorm[p0 + t] = 1.0f / fmaxf(sqrtf(s), 1e-12f);   // matches F.normalize eps clamp
    }
}

// ---------------- kernel 2: |k|^2 (FLT_MAX for padding) ----------------
__global__ __launch_bounds__(256) void k_kn(const float* __restrict__ keys,
                                            float* __restrict__ kn) {
    int wave = threadIdx.x >> 6;
    int lane = threadIdx.x & 63;
    int m = blockIdx.x * 4 + wave;                   // grid 512 -> m in [0,2048)
    float s = 0.f;
    if (m < M_) {
        const float4* row = (const float4*)(keys + (size_t)m * D_);
        for (int j = lane; j < D_ / 4; j += 64) {    // 128 float4 -> 2 per lane
            float4 v = row[j];
            s += v.x * v.x + v.y * v.y + v.z * v.z + v.w * v.w;
        }
    }
    for (int off = 32; off; off >>= 1) s += __shfl_down(s, off, 64);
    if (lane == 0) kn[m] = (m < M_) ? s : FLT_MAX;
}

// ---------------- kernel 3: keys (M,D) -> keysT (D, MP) zero-padded ----------------
__global__ __launch_bounds__(256) void k_transpose(const float* __restrict__ keys,
                                                   float* __restrict__ keysT) {
    __shared__ float tile[64][65];
    int t = threadIdx.x;
    int m0 = (blockIdx.x & 31) * 64;                 // 32 m-tiles
    int d0 = (blockIdx.x >> 5) * 64;                 // 8 d-tiles
#pragma unroll
    for (int i = 0; i < 4; ++i) {
        int slot = t + 256 * i;                      // 0..1023 float4 slots
        int ml = slot >> 4;
        int d4 = (slot & 15) * 4;
        int m = m0 + ml;
        float4 v = make_float4(0.f, 0.f, 0.f, 0.f);
        if (m < M_) v = *(const float4*)(keys + (size_t)m * D_ + d0 + d4);
        tile[ml][d4 + 0] = v.x; tile[ml][d4 + 1] = v.y;
        tile[ml][d4 + 2] = v.z; tile[ml][d4 + 3] = v.w;
    }
    __syncthreads();
#pragma unroll
    for (int i = 0; i < 4; ++i) {
        int slot = t + 256 * i;
        int dl = slot >> 4;
        int m4 = (slot & 15) * 4;
        float4 v = make_float4(tile[m4 + 0][dl], tile[m4 + 1][dl],
                               tile[m4 + 2][dl], tile[m4 + 3][dl]);
        *(float4*)(keysT + (size_t)(d0 + dl) * MP_ + m0 + m4) = v;
    }
}

// ---------------- kernel 4: fused fp32 GEMM + running top-2 argmin ----------------
// Tile: 64 pixels x 128 keys, DK=32 per stage. 128 threads, 8x8 register tile each.
// grid (N/64, 2): y splits the key range (2x blocks -> 4 blocks/CU for latency hiding).
constexpr int NT = 64, MT = 128, DK = 32;

__global__ __launch_bounds__(128) void k_score(
    const float* __restrict__ q, const float* __restrict__ keysT,
    const float* __restrict__ kn, const float* __restrict__ rnorm,
    uint2* __restrict__ best)
{
    __shared__ float smem[DK * NT + DK * MT];        // 24 KiB; reused for the reduce
    float* As = smem;                                // [DK][NT]  (d-major, pixel contiguous)
    float* Ks = smem + DK * NT;                      // [DK][MT]  (d-major, key contiguous)

    int t = threadIdx.x;
    int pg = t & 7, kg = t >> 3;
    int p0 = blockIdx.x * NT;
    const float* qbase = q + (size_t)(p0 / HW_) * (D_ * HW_) + (p0 % HW_);

    float rn[8];
#pragma unroll
    for (int i = 0; i < 8; ++i) rn[i] = rnorm[p0 + pg * 8 + i];

    float min1[8], min2[8];
    unsigned idx1[8], idx2[8];
#pragma unroll
    for (int i = 0; i < 8; ++i) { min1[i] = FLT_MAX; min2[i] = FLT_MAX; idx1[i] = 0; idx2[i] = 0; }

    int mc_beg = blockIdx.y * 8;                     // each y-half: 8 chunks of 128 keys
    for (int mc = mc_beg; mc < mc_beg + 8; ++mc) {
        int m0 = mc * MT;
        float acc[8][8];
#pragma unroll
        for (int pi = 0; pi < 8; ++pi)
#pragma unroll
            for (int ki = 0; ki < 8; ++ki) acc[pi][ki] = 0.f;

        for (int dc = 0; dc < D_ / DK; ++dc) {       // 16 stages of DK=32
            int d0 = dc * DK;
            __syncthreads();
            // stage A: 512 float4, coalesced (contiguous hw), no transpose needed
#pragma unroll
            for (int i = 0; i < 4; ++i) {
                int slot = t + 128 * i;
                int c  = slot >> 4;
                int p4 = (slot & 15) * 4;
                ((float4*)As)[slot] = *(const float4*)(qbase + (size_t)(d0 + c) * HW_ + p4);
            }
            // stage K: 1024 float4 from pre-transposed keysT, coalesced
#pragma unroll
            for (int i = 0; i < 8; ++i) {
                int slot = t + 128 * i;
                int d  = slot >> 5;
                int m4 = (slot & 31) * 4;
                ((float4*)Ks)[slot] = *(const float4*)(keysT + (size_t)(d0 + d) * MP_ + m0 + m4);
            }
            __syncthreads();
#pragma unroll
            for (int d = 0; d < DK; ++d) {
                float a[8], bb[8];
                *(float4*)&a[0]  = *(float4*)&As[d * NT + pg * 8];
                *(float4*)&a[4]  = *(float4*)&As[d * NT + pg * 8 + 4];
                *(float4*)&bb[0] = *(float4*)&Ks[d * MT + kg * 8];
                *(float4*)&bb[4] = *(float4*)&Ks[d * MT + kg * 8 + 4];
#pragma unroll
                for (int pi = 0; pi < 8; ++pi)
#pragma unroll
                    for (int ki = 0; ki < 8; ++ki)
                        acc[pi][ki] = fmaf(a[pi], bb[ki], acc[pi][ki]);
            }
        }
        // fold this 128-key chunk into the running per-pixel top-2
        // (ki ascending == m ascending; strict '<' keeps the earliest index on ties)
#pragma unroll
        for (int ki = 0; ki < 8; ++ki) {
            unsigned m = (unsigned)(m0 + kg * 8 + ki);
            float kv = kn[m];                        // FLT_MAX for padded keys -> never win
#pragma unroll
            for (int pi = 0; pi < 8; ++pi) {
                float s = fmaf(-2.0f * rn[pi], acc[pi][ki], kv);  // |q|^2 const, drops out
                if (s < min1[pi]) { min2[pi] = min1[pi]; idx2[pi] = idx1[pi];
                                    min1[pi] = s;        idx1[pi] = m; }
                else if (s < min2[pi]) { min2[pi] = s; idx2[pi] = m; }
            }
        }
    }

    // cross-thread (kg) merge of per-pixel top-2 lists via LDS
    __syncthreads();
    float4* red = (float4*)smem;                     // [64][17] padded, 17408 B < 24 KiB
#pragma unroll
    for (int pi = 0; pi < 8; ++pi) {
        red[(pg * 8 + pi) * 17 + kg] =
            make_float4(min1[pi], __uint_as_float(idx1[pi]),
                        min2[pi], __uint_as_float(idx2[pi]));
    }
    __syncthreads();
    if (t < 64) {
        float m1 = FLT_MAX, m2 = FLT_MAX;
        unsigned i1 = 0, i2 = 0;
        for (int g = 0; g < 16; ++g) {               // kg ascending == m ascending
            float4 e = red[t * 17 + g];
            float s = e.x; unsigned ix = __float_as_uint(e.y);
            if (s < m1) { m2 = m1; i2 = i1; m1 = s; i1 = ix; }
            else if (s < m2) { m2 = s; i2 = ix; }
            s = e.z; ix = __float_as_uint(e.w);
            if (s < m1) { m2 = m1; i2 = i1; m1 = s; i1 = ix; }
            else if (s < m2) { m2 = s; i2 = ix; }
        }
        best[(size_t)blockIdx.y * N_ + p0 + t] = make_uint2(i1, i2);
    }
}

// ---------------- kernel 5: exact fp32 rescue over 4 candidates + heatmap ----------------
__global__ __launch_bounds__(256) void k_heat(
    const float* __restrict__ q, const float* __restrict__ keys,
    const float* __restrict__ kn, const float* __restrict__ rnorm,
    const uint2* __restrict__ best, float* __restrict__ out)
{
    int p = blockIdx.x * 256 + threadIdx.x;          // 4096 % 256 == 0 -> one batch/block
    const float* qb = q + (size_t)(p / HW_) * (D_ * HW_) + (p % HW_);
    uint2 c0 = best[p];
    uint2 c1 = best[N_ + p];
    unsigned cand[4] = { c0.x, c0.y, c1.x, c1.y };
    float rn = rnorm[p];
    const float* kp[4];
#pragma unroll
    for (int i = 0; i < 4; ++i) kp[i] = keys + (size_t)cand[i] * D_;
    float dot[4] = {0.f, 0.f, 0.f, 0.f}, hh[4] = {0.f, 0.f, 0.f, 0.f};
    for (int c = 0; c < D_; c += 4) {
        float qv[4];
#pragma unroll
        for (int j = 0; j < 4; ++j) qv[j] = qb[(size_t)(c + j) * HW_] * rn;  // coalesced
#pragma unroll
        for (int i = 0; i < 4; ++i) {
            float4 kv = *(const float4*)(kp[i] + c);                          // L2 gather
            dot[i] += qv[0] * kv.x + qv[1] * kv.y + qv[2] * kv.z + qv[3] * kv.w;
            float d0 = qv[0] - kv.x, d1 = qv[1] - kv.y, d2 = qv[2] - kv.z, d3 = qv[3] - kv.w;
            float e0 = d0 * d0, e1 = d1 * d1, e2 = d2 * d2, e3 = d3 * d3;
            hh[i] += e0 * e0 + e1 * e1 + e2 * e2 + e3 * e3;
        }
    }
    float bs = FLT_MAX; unsigned bi = 0xFFFFFFFFu; float bh = 0.f;
#pragma unroll
    for (int i = 0; i < 4; ++i) {
        float s = kn[cand[i]] - 2.0f * dot[i];
        // argmin semantics: smaller score wins; exact tie -> smaller index (first occurrence)
        if (s < bs || (s == bs && cand[i] < bi)) { bs = s; bi = cand[i]; bh = hh[i]; }
    }
    out[p] = bh;
}

extern "C" void kernel_launch(void* const* d_in, const int* in_sizes, int n_in,
                              void* d_out, int out_size, void* d_ws, size_t ws_size,
                              hipStream_t stream) {
    const float* query = (const float*)d_in[0];   // (8,512,64,64) f32
    const float* keys  = (const float*)d_in[1];   // (2000,512) f32
    float* out = (float*)d_out;                   // 32768 f32

    // workspace layout (~4.9 MB total, rewritten every launch):
    float* ws    = (float*)d_ws;
    float* keysT = ws;                            // 512*2048 f32 (4 MiB)
    float* rnorm = ws + (size_t)D_ * MP_;         // 32768 f32
    float* kn    = rnorm + N_;                    // 2048 f32
    uint2* best  = (uint2*)(kn + MP_);            // 2 * 32768 uint2 (512 KiB)

    k_rnorm    <<<N_ / 128,              256, 0, stream>>>(query, rnorm);
    k_kn       <<<MP_ / 4,               256, 0, stream>>>(keys, kn);
    k_transpose<<<(MP_ / 64) * (D_ / 64),256, 0, stream>>>(keys, keysT);
    k_score    <<<dim3(N_ / NT, 2),      128, 0, stream>>>(query, keysT, kn, rnorm, best);
    k_heat     <<<N_ / 256,              256, 0, stream>>>(query, keys, kn, rnorm, best, out);
}

// Round 2
// 358.420 us; speedup vs baseline: 3.0717x; 3.0717x over previous
//
#include <hip/hip_runtime.h>
#include <float.h>
#include <math.h>

// Problem constants: query (8,512,64,64) f32, keys (2000,512) f32
constexpr int D_  = 512;
constexpr int HW_ = 4096;           // 64*64
constexpr int N_  = 32768;          // B*HW
constexpr int M_  = 2000;
constexpr int MP_ = 2048;           // padded key count

typedef _Float16 half8 __attribute__((ext_vector_type(8)));
typedef float    f32x4 __attribute__((ext_vector_type(4)));

// async global->LDS, 16B per lane. LDS dest = base (wave-uniform) + lane*16.
__device__ inline void async16(void* lds, const void* g) {
    __builtin_amdgcn_global_load_lds(
        (const __attribute__((address_space(1))) unsigned int*)g,
        (__attribute__((address_space(3))) unsigned int*)lds, 16, 0, 0);
}

// ---------------- kernel 1: per-pixel reciprocal norms ----------------
__global__ __launch_bounds__(256) void k_rnorm(const float* __restrict__ q,
                                               float* __restrict__ rnorm) {
    __shared__ float part[128][5];
    int t = threadIdx.x;
    int pl = t & 63, cg = t >> 6;
    int p0 = blockIdx.x * 128;
    const float* base = q + (size_t)(p0 / HW_) * (D_ * HW_) + (p0 % HW_);
    float s0 = 0.f, s1 = 0.f;
    int cbeg = cg * 128;
    for (int c = cbeg; c < cbeg + 128; ++c) {
        float v0 = base[(size_t)c * HW_ + pl];
        float v1 = base[(size_t)c * HW_ + 64 + pl];
        s0 += v0 * v0;
        s1 += v1 * v1;
    }
    part[pl][cg] = s0;
    part[pl + 64][cg] = s1;
    __syncthreads();
    if (t < 128) {
        float s = part[t][0] + part[t][1] + part[t][2] + part[t][3];
        rnorm[p0 + t] = 1.0f / fmaxf(sqrtf(s), 1e-12f);
    }
}

// ---------------- kernel 2: |k|^2 (FLT_MAX for padding) ----------------
__global__ __launch_bounds__(256) void k_kn(const float* __restrict__ keys,
                                            float* __restrict__ kn) {
    int wave = threadIdx.x >> 6;
    int lane = threadIdx.x & 63;
    int m = blockIdx.x * 4 + wave;
    float s = 0.f;
    if (m < M_) {
        const float4* row = (const float4*)(keys + (size_t)m * D_);
        for (int j = lane; j < D_ / 4; j += 64) {
            float4 v = row[j];
            s += v.x * v.x + v.y * v.y + v.z * v.z + v.w * v.w;
        }
    }
    for (int off = 32; off; off >>= 1) s += __shfl_down(s, off, 64);
    if (lane == 0) kn[m] = (m < M_) ? s : FLT_MAX;
}

// ---------------- kernel 3: q -> normalized fp16, MFMA A-fragment order ----------------
// qsw[pb][kb][lane][j]: lane L holds A[m = pb*16 + (L&15)][k = kb*32 + (L>>4)*8 + j]
__global__ __launch_bounds__(256) void k_qsw(const float* __restrict__ q,
                                             const float* __restrict__ rnorm,
                                             _Float16* __restrict__ qsw) {
    __shared__ float tile[64][65];
    __shared__ float rns[64];
    int t = threadIdx.x;
    int pt = blockIdx.x & 511;            // pixel tile (64 pixels, within one batch)
    int ct = blockIdx.x >> 9;             // c tile (64 channels)
    int p0 = pt * 64;
    const float* base = q + ((size_t)(p0 / HW_) * D_ + ct * 64) * HW_ + (p0 % HW_);
    if (t < 64) rns[t] = rnorm[p0 + t];
#pragma unroll
    for (int i = 0; i < 4; ++i) {
        int s = t + 256 * i;              // 1024 float4 slots: 64 rows x 16
        int row = s >> 4, p4 = (s & 15) * 4;
        float4 v = *(const float4*)(base + (size_t)row * HW_ + p4);
        tile[row][p4 + 0] = v.x; tile[row][p4 + 1] = v.y;
        tile[row][p4 + 2] = v.z; tile[row][p4 + 3] = v.w;
    }
    __syncthreads();
    int pb0 = pt * 4;
#pragma unroll
    for (int i = 0; i < 2; ++i) {
        int f = t + 256 * i;              // 512 fragments: 8 tiles x 64 lanes
        int ti = f >> 6, L = f & 63;
        int pbi = ti & 3, kbi = ti >> 2;
        int pl = pbi * 16 + (L & 15);
        int cl = kbi * 32 + ((L >> 4) * 8);
        float rn = rns[pl];
        half8 hv;
#pragma unroll
        for (int j = 0; j < 8; ++j) hv[j] = (_Float16)(tile[cl + j][pl] * rn);
        size_t off = (((size_t)(pb0 + pbi) * 16 + (ct * 2 + kbi)) * 64 + L) * 8;
        *(half8*)(qsw + off) = hv;
    }
}

// ---------------- kernel 4: keys -> fp16, MFMA B-fragment order ----------------
// ksw[nb][kb][lane][j]: lane L holds B[k = kb*32 + (L>>4)*8 + j][n = nb*16 + (L&15)]
//                       = keys[nb*16 + (L&15)][kb*32 + (L>>4)*8 + j]  (k-contiguous!)
__global__ __launch_bounds__(256) void k_ksw(const float* __restrict__ keys,
                                             _Float16* __restrict__ ksw) {
    int f = blockIdx.x * 256 + threadIdx.x;   // 131072 fragments
    int nb = f >> 10, rest = f & 1023;
    int kb = rest >> 6, L = rest & 63;
    int m = nb * 16 + (L & 15);
    int c = kb * 32 + ((L >> 4) * 8);
    half8 hv;
    if (m < M_) {
        float4 v0 = *(const float4*)(keys + (size_t)m * D_ + c);
        float4 v1 = *(const float4*)(keys + (size_t)m * D_ + c + 4);
        hv[0] = (_Float16)v0.x; hv[1] = (_Float16)v0.y;
        hv[2] = (_Float16)v0.z; hv[3] = (_Float16)v0.w;
        hv[4] = (_Float16)v1.x; hv[5] = (_Float16)v1.y;
        hv[6] = (_Float16)v1.z; hv[7] = (_Float16)v1.w;
    } else {
#pragma unroll
        for (int j = 0; j < 8; ++j) hv[j] = (_Float16)0.f;
    }
    *(half8*)(ksw + (size_t)f * 8) = hv;
}

// merge top-2 list (t1,j1,t2,j2) into (s1,i1,s2,i2); both sorted; idx tie-break.
__device__ inline void merge2(float& s1, unsigned& i1, float& s2, unsigned& i2,
                              float t1, unsigned j1, float t2, unsigned j2) {
    if (t1 < s1 || (t1 == s1 && j1 < i1)) {
        float os = s1; unsigned oi = i1;
        s1 = t1; i1 = j1;
        if (os < t2 || (os == t2 && oi < j2)) { s2 = os; i2 = oi; }
        else { s2 = t2; i2 = j2; }
    } else {
        if (t1 < s2 || (t1 == s2 && j1 < i2)) { s2 = t1; i2 = j1; }
    }
}

// ---------------- kernel 5: MFMA score GEMM + fused per-chunk top-2 ----------------
// grid (N/128, MP/128). 256 thr = 4 waves in 2x2; wave = 64x64 out = 4x4 16x16 frags.
__global__ __launch_bounds__(256) void k_mfma(const _Float16* __restrict__ qsw,
                                              const _Float16* __restrict__ ksw,
                                              const float* __restrict__ kn,
                                              const float* __restrict__ rnorm,
                                              float4* __restrict__ best) {
    __shared__ _Float16 As[16 * 512];     // 16 KiB: 16 tiles (kbi*8+pbi) x 1024B
    __shared__ _Float16 Bs[16 * 512];     // 16 KiB
    int t = threadIdx.x;
    int lane = t & 63;
    int w = __builtin_amdgcn_readfirstlane(t >> 6);
    int wr = w >> 1, wc = w & 1;
    int p0 = blockIdx.x * 128;
    int m0 = blockIdx.y * 128;
    int pb0 = p0 >> 4, nb0 = m0 >> 4;

    f32x4 acc[4][4];
#pragma unroll
    for (int pi = 0; pi < 4; ++pi)
#pragma unroll
        for (int ni = 0; ni < 4; ++ni) acc[pi][ni] = (f32x4){0.f, 0.f, 0.f, 0.f};

    for (int dc = 0; dc < D_ / 64; ++dc) {        // 8 K-steps of 64
        int kb0 = dc * 2;
        __syncthreads();                          // prior readers done
#pragma unroll
        for (int i = 0; i < 4; ++i) {             // wave w stages tiles w*4..w*4+3 of A and B
            int ti = w * 4 + i;
            int kbi = ti >> 3, pbi = ti & 7;      // also nbi for B
            const _Float16* ga = qsw + (((size_t)(pb0 + pbi) * 16 + (kb0 + kbi)) * 64 + lane) * 8;
            async16(&As[ti * 512], ga);
            const _Float16* gb = ksw + (((size_t)(nb0 + pbi) * 16 + (kb0 + kbi)) * 64 + lane) * 8;
            async16(&Bs[ti * 512], gb);
        }
        __syncthreads();                          // staging drained (vmcnt(0) at barrier)
#pragma unroll
        for (int kbi = 0; kbi < 2; ++kbi) {
            half8 a[4], b[4];
#pragma unroll
            for (int pi = 0; pi < 4; ++pi)
                a[pi] = *(const half8*)&As[(kbi * 8 + wr * 4 + pi) * 512 + lane * 8];
#pragma unroll
            for (int ni = 0; ni < 4; ++ni)
                b[ni] = *(const half8*)&Bs[(kbi * 8 + wc * 4 + ni) * 512 + lane * 8];
#pragma unroll
            for (int pi = 0; pi < 4; ++pi)
#pragma unroll
                for (int ni = 0; ni < 4; ++ni)
                    acc[pi][ni] = __builtin_amdgcn_mfma_f32_16x16x32_f16(a[pi], b[ni], acc[pi][ni], 0, 0, 0);
        }
    }

    // ---- epilogue: scores + per-pixel top-2 over this block's 128 keys ----
    int colk = lane & 15, quad = lane >> 4;
    float knv[4];
#pragma unroll
    for (int ni = 0; ni < 4; ++ni) knv[ni] = kn[m0 + wc * 64 + ni * 16 + colk];

    __syncthreads();                              // all waves done with As/Bs
    float4* red = (float4*)(void*)As;             // [128 pixels][2 waves], 4 KiB

#pragma unroll
    for (int pi = 0; pi < 4; ++pi) {
#pragma unroll
        for (int r = 0; r < 4; ++r) {
            int pix = wr * 64 + pi * 16 + quad * 4 + r;   // C/D: row = quad*4 + reg
            float rn = rnorm[p0 + pix];
            float s1 = FLT_MAX, s2 = FLT_MAX;
            unsigned i1 = 0xFFFFFFFFu, i2 = 0xFFFFFFFFu;
#pragma unroll
            for (int ni = 0; ni < 4; ++ni) {
                float s = fmaf(-2.0f * rn, acc[pi][ni][r], knv[ni]);
                unsigned ix = (unsigned)(m0 + wc * 64 + ni * 16 + colk);
                if (s < s1 || (s == s1 && ix < i1)) { s2 = s1; i2 = i1; s1 = s; i1 = ix; }
                else if (s < s2 || (s == s2 && ix < i2)) { s2 = s; i2 = ix; }
            }
            // butterfly over the 16 cols holding this pixel
#pragma unroll
            for (int mask = 1; mask < 16; mask <<= 1) {
                float t1 = __shfl_xor(s1, mask, 64);
                float t2 = __shfl_xor(s2, mask, 64);
                unsigned j1 = (unsigned)__shfl_xor((int)i1, mask, 64);
                unsigned j2 = (unsigned)__shfl_xor((int)i2, mask, 64);
                merge2(s1, i1, s2, i2, t1, j1, t2, j2);
            }
            if (colk == 0)
                red[pix * 2 + wc] = make_float4(s1, __uint_as_float(i1),
                                                s2, __uint_as_float(i2));
        }
    }
    __syncthreads();
    if (t < 128) {
        float4 e0 = red[t * 2 + 0];
        float4 e1 = red[t * 2 + 1];
        float s1 = e0.x, s2 = e0.z;
        unsigned i1 = __float_as_uint(e0.y), i2 = __float_as_uint(e0.w);
        merge2(s1, i1, s2, i2, e1.x, __float_as_uint(e1.y), e1.z, __float_as_uint(e1.w));
        best[(size_t)blockIdx.y * N_ + p0 + t] =
            make_float4(s1, __uint_as_float(i1), s2, __uint_as_float(i2));
    }
}

// ---------------- kernel 6: merge 16 chunks -> top-4, exact fp32 rescue + heatmap ----------------
__global__ __launch_bounds__(256) void k_heat(
    const float* __restrict__ q, const float* __restrict__ keys,
    const float* __restrict__ kn, const float* __restrict__ rnorm,
    const float4* __restrict__ best, float* __restrict__ out)
{
    int p = blockIdx.x * 256 + threadIdx.x;
    const float* qb = q + (size_t)(p / HW_) * (D_ * HW_) + (p % HW_);
    float cs[4] = {FLT_MAX, FLT_MAX, FLT_MAX, FLT_MAX};
    unsigned ci[4] = {0xFFFFFFFFu, 0xFFFFFFFFu, 0xFFFFFFFFu, 0xFFFFFFFFu};
#pragma unroll 4
    for (int ch = 0; ch < MP_ / 128; ++ch) {
        float4 e = best[(size_t)ch * N_ + p];
#pragma unroll
        for (int h = 0; h < 2; ++h) {
            float s = h ? e.z : e.x;
            unsigned ix = __float_as_uint(h ? e.w : e.y);
            if (s < cs[3] || (s == cs[3] && ix < ci[3])) {
                cs[3] = s; ci[3] = ix;
#pragma unroll
                for (int k = 3; k > 0; --k) {
                    if (cs[k] < cs[k - 1] || (cs[k] == cs[k - 1] && ci[k] < ci[k - 1])) {
                        float ts = cs[k]; cs[k] = cs[k - 1]; cs[k - 1] = ts;
                        unsigned ti = ci[k]; ci[k] = ci[k - 1]; ci[k - 1] = ti;
                    }
                }
            }
        }
    }
    float rn = rnorm[p];
    const float* kp[4];
#pragma unroll
    for (int i = 0; i < 4; ++i) kp[i] = keys + (size_t)ci[i] * D_;
    float dot[4] = {0.f, 0.f, 0.f, 0.f}, hh[4] = {0.f, 0.f, 0.f, 0.f};
    for (int c = 0; c < D_; c += 4) {
        float qv[4];
#pragma unroll
        for (int j = 0; j < 4; ++j) qv[j] = qb[(size_t)(c + j) * HW_] * rn;
#pragma unroll
        for (int i = 0; i < 4; ++i) {
            float4 kv = *(const float4*)(kp[i] + c);
            dot[i] += qv[0] * kv.x + qv[1] * kv.y + qv[2] * kv.z + qv[3] * kv.w;
            float d0 = qv[0] - kv.x, d1 = qv[1] - kv.y, d2 = qv[2] - kv.z, d3 = qv[3] - kv.w;
            float e0 = d0 * d0, e1 = d1 * d1, e2 = d2 * d2, e3 = d3 * d3;
            hh[i] += e0 * e0 + e1 * e1 + e2 * e2 + e3 * e3;
        }
    }
    float bs = FLT_MAX; unsigned bi = 0xFFFFFFFFu; float bh = 0.f;
#pragma unroll
    for (int i = 0; i < 4; ++i) {
        float s = kn[ci[i]] - 2.0f * dot[i];
        if (s < bs || (s == bs && ci[i] < bi)) { bs = s; bi = ci[i]; bh = hh[i]; }
    }
    out[p] = bh;
}

extern "C" void kernel_launch(void* const* d_in, const int* in_sizes, int n_in,
                              void* d_out, int out_size, void* d_ws, size_t ws_size,
                              hipStream_t stream) {
    const float* query = (const float*)d_in[0];   // (8,512,64,64) f32
    const float* keys  = (const float*)d_in[1];   // (2000,512) f32
    float* out = (float*)d_out;                   // 32768 f32

    // workspace layout (~44 MB):
    char* ws = (char*)d_ws;
    _Float16* qsw  = (_Float16*)ws;                                  // N*D fp16   = 33.5 MB
    _Float16* ksw  = (_Float16*)(ws + (size_t)N_ * D_ * 2);          // MP*D fp16  = 2 MB
    float*    rnorm = (float*)(ws + (size_t)N_ * D_ * 2 + (size_t)MP_ * D_ * 2);
    float*    kn    = rnorm + N_;
    float4*   best  = (float4*)(kn + MP_);                           // 16*N float4 = 8 MB

    k_rnorm<<<N_ / 128,            256, 0, stream>>>(query, rnorm);
    k_kn   <<<MP_ / 4,             256, 0, stream>>>(keys, kn);
    k_ksw  <<<MP_ * D_ / 8 / 256,  256, 0, stream>>>(keys, ksw);
    k_qsw  <<<(N_ / 64) * (D_ / 64), 256, 0, stream>>>(query, rnorm, qsw);
    k_mfma <<<dim3(N_ / 128, MP_ / 128), 256, 0, stream>>>(qsw, ksw, kn, rnorm, best);
    k_heat <<<N_ / 256,            256, 0, stream>>>(query, keys, kn, rnorm, best, out);
}

// Round 4
// 251.622 us; speedup vs baseline: 4.3754x; 1.4244x over previous
//
#include <hip/hip_runtime.h>
#include <float.h>
#include <math.h>

// Problem constants: query (8,512,64,64) f32, keys (2000,512) f32
constexpr int D_  = 512;
constexpr int HW_ = 4096;           // 64*64
constexpr int N_  = 32768;          // B*HW
constexpr int M_  = 2000;
constexpr int MP_ = 2048;           // padded key count

typedef _Float16 half8 __attribute__((ext_vector_type(8)));
typedef float    f32x4 __attribute__((ext_vector_type(4)));

// async global->LDS, 16B per lane. LDS dest = base (wave-uniform) + lane*16.
__device__ inline void async16(void* lds, const void* g) {
    __builtin_amdgcn_global_load_lds(
        (const __attribute__((address_space(1))) unsigned int*)g,
        (__attribute__((address_space(3))) unsigned int*)lds, 16, 0, 0);
}

// ---------------- kernel 1: fused per-pixel rnorm + fp16 A-fragment swizzle ----------------
// qsw holds NORMALIZED q-hat. Scores downstream must therefore use s = kn - 2*acc
// (NO extra rnorm factor — double-applying rnorm was the R3 correctness bug).
// qsw[pb][kb][lane][j]: lane L holds A[m = pb*16 + (L&15)][k = kb*32 + (L>>4)*8 + j]
__global__ __launch_bounds__(256) void k_prep(const float* __restrict__ q,
                                              float* __restrict__ rnorm,
                                              _Float16* __restrict__ qsw) {
    __shared__ float tile[64][65];
    __shared__ float part[64][5];
    __shared__ float rns[64];
    int t = threadIdx.x;
    int pl = t & 63, cg = t >> 6;
    int p0 = blockIdx.x * 64;                    // 64 | 4096 -> single batch per block
    const float* base = q + (size_t)(p0 / HW_) * (D_ * HW_) + (p0 % HW_);

    float s = 0.f;
    for (int c = cg * 128; c < cg * 128 + 128; ++c) {
        float v = base[(size_t)c * HW_ + pl];    // coalesced along hw
        s += v * v;
    }
    part[pl][cg] = s;
    __syncthreads();
    if (t < 64) {
        float ss = part[t][0] + part[t][1] + part[t][2] + part[t][3];
        float rv = 1.0f / fmaxf(sqrtf(ss), 1e-12f);   // matches F.normalize eps
        rns[t] = rv;
        rnorm[p0 + t] = rv;
    }

    int pb0 = blockIdx.x * 4;
    for (int ct = 0; ct < 8; ++ct) {
        __syncthreads();                         // tile free (prev readers done) + rns ready
#pragma unroll
        for (int i = 0; i < 4; ++i) {
            int sl = t + 256 * i;                // 1024 float4 slots: 64 ch-rows x 16
            int row = sl >> 4, p4 = (sl & 15) * 4;
            float4 v = *(const float4*)(base + (size_t)(ct * 64 + row) * HW_ + p4);
            tile[row][p4 + 0] = v.x; tile[row][p4 + 1] = v.y;
            tile[row][p4 + 2] = v.z; tile[row][p4 + 3] = v.w;
        }
        __syncthreads();
#pragma unroll
        for (int i = 0; i < 2; ++i) {
            int f = t + 256 * i;                 // 512 fragments: 8 tiles x 64 lanes
            int ti = f >> 6, L = f & 63;
            int pbi = ti & 3, kbi = ti >> 2;
            int plx = pbi * 16 + (L & 15);
            int cl = kbi * 32 + ((L >> 4) * 8);
            float rv = rns[plx];
            half8 hv;
#pragma unroll
            for (int j = 0; j < 8; ++j) hv[j] = (_Float16)(tile[cl + j][plx] * rv);
            size_t off = (((size_t)(pb0 + pbi) * 16 + (ct * 2 + kbi)) * 64 + L) * 8;
            *(half8*)(qsw + off) = hv;
        }
    }
}

// ---------------- kernel 2: |k|^2 (FLT_MAX for padding) ----------------
__global__ __launch_bounds__(256) void k_kn(const float* __restrict__ keys,
                                            float* __restrict__ kn) {
    int wave = threadIdx.x >> 6;
    int lane = threadIdx.x & 63;
    int m = blockIdx.x * 4 + wave;
    float s = 0.f;
    if (m < M_) {
        const float4* row = (const float4*)(keys + (size_t)m * D_);
        for (int j = lane; j < D_ / 4; j += 64) {
            float4 v = row[j];
            s += v.x * v.x + v.y * v.y + v.z * v.z + v.w * v.w;
        }
    }
    for (int off = 32; off; off >>= 1) s += __shfl_down(s, off, 64);
    if (lane == 0) kn[m] = (m < M_) ? s : FLT_MAX;
}

// ---------------- kernel 3: keys -> fp16, MFMA B-fragment order ----------------
// ksw[nb][kb][lane][j]: lane L holds B[k][n=nb*16+(L&15)] = keys[n][kb*32+(L>>4)*8+j]
__global__ __launch_bounds__(256) void k_ksw(const float* __restrict__ keys,
                                             _Float16* __restrict__ ksw) {
    int f = blockIdx.x * 256 + threadIdx.x;      // 131072 fragments
    int nb = f >> 10, rest = f & 1023;
    int kb = rest >> 6, L = rest & 63;
    int m = nb * 16 + (L & 15);
    int c = kb * 32 + ((L >> 4) * 8);
    half8 hv;
    if (m < M_) {
        float4 v0 = *(const float4*)(keys + (size_t)m * D_ + c);
        float4 v1 = *(const float4*)(keys + (size_t)m * D_ + c + 4);
        hv[0] = (_Float16)v0.x; hv[1] = (_Float16)v0.y;
        hv[2] = (_Float16)v0.z; hv[3] = (_Float16)v0.w;
        hv[4] = (_Float16)v1.x; hv[5] = (_Float16)v1.y;
        hv[6] = (_Float16)v1.z; hv[7] = (_Float16)v1.w;
    } else {
#pragma unroll
        for (int j = 0; j < 8; ++j) hv[j] = (_Float16)0.f;
    }
    *(half8*)(ksw + (size_t)f * 8) = hv;
}

// merge top-2 list (t1,j1,t2,j2) into (s1,i1,s2,i2); both sorted; idx tie-break.
__device__ inline void merge2(float& s1, unsigned& i1, float& s2, unsigned& i2,
                              float t1, unsigned j1, float t2, unsigned j2) {
    if (t1 < s1 || (t1 == s1 && j1 < i1)) {
        float os = s1; unsigned oi = i1;
        s1 = t1; i1 = j1;
        if (os < t2 || (os == t2 && oi < j2)) { s2 = os; i2 = oi; }
        else { s2 = t2; i2 = j2; }
    } else {
        if (t1 < s2 || (t1 == s2 && j1 < i2)) { s2 = t1; i2 = j1; }
    }
}

// ---------------- kernel 4: MFMA score GEMM, chunk loop + packed running top-2 ----------------
// grid (N/128, 2). Block: 128 pixels x 1024 keys (8 chunks of 128), 4 waves in 2x2.
// acc = q-hat . k (qsw pre-normalized) -> score s = kn - 2*acc. Always positive
// (s >= |k|(|k|-2), |k|~22) -> float bits compare as unsigned. Pack thread-local
// key id (5 bits) into low mantissa: top-2 fold = 3 int min/max; trunc error
// 32 ulp ~ 2e-3 ~ fp16 GEMM noise (both absorbed by the exact fp32 rescue).
__global__ __launch_bounds__(256) void k_mfma(const _Float16* __restrict__ qsw,
                                              const _Float16* __restrict__ ksw,
                                              const float* __restrict__ kn,
                                              float4* __restrict__ best) {
    __shared__ _Float16 As[16 * 512];            // 16 KiB: 16 tiles (kbi*8+pbi) x 1024B
    __shared__ _Float16 Bs[16 * 512];            // 16 KiB
    int t = threadIdx.x;
    int lane = t & 63;
    int w = __builtin_amdgcn_readfirstlane(t >> 6);
    int wr = w >> 1, wc = w & 1;
    int colk = lane & 15, quad = lane >> 4;
    int p0 = blockIdx.x * 128;
    int yb = blockIdx.y;                         // key half: yb*1024
    int pb0 = p0 >> 4;

    unsigned pk1[16], pk2[16];
#pragma unroll
    for (int i = 0; i < 16; ++i) { pk1[i] = 0xFFFFFFFFu; pk2[i] = 0xFFFFFFFFu; }

    for (int ch = 0; ch < 8; ++ch) {
        int m0 = yb * 1024 + ch * 128;
        int nb0 = m0 >> 4;
        f32x4 acc[4][4];
#pragma unroll
        for (int pi = 0; pi < 4; ++pi)
#pragma unroll
            for (int ni = 0; ni < 4; ++ni) acc[pi][ni] = (f32x4){0.f, 0.f, 0.f, 0.f};

        for (int dc = 0; dc < 8; ++dc) {         // K-steps of 64
            int kb0 = dc * 2;
            __syncthreads();                     // prior readers done
#pragma unroll
            for (int i = 0; i < 4; ++i) {        // wave w stages tiles w*4..w*4+3
                int ti = w * 4 + i;
                int kbi = ti >> 3, pbi = ti & 7; // pbi doubles as nbi for B
                async16(&As[ti * 512],
                        qsw + (((size_t)(pb0 + pbi) * 16 + (kb0 + kbi)) * 64 + lane) * 8);
                async16(&Bs[ti * 512],
                        ksw + (((size_t)(nb0 + pbi) * 16 + (kb0 + kbi)) * 64 + lane) * 8);
            }
            __syncthreads();                     // staging drained
#pragma unroll
            for (int kbi = 0; kbi < 2; ++kbi) {
                half8 a[4], b[4];
#pragma unroll
                for (int pi = 0; pi < 4; ++pi)
                    a[pi] = *(const half8*)&As[(kbi * 8 + wr * 4 + pi) * 512 + lane * 8];
#pragma unroll
                for (int ni = 0; ni < 4; ++ni)
                    b[ni] = *(const half8*)&Bs[(kbi * 8 + wc * 4 + ni) * 512 + lane * 8];
#pragma unroll
                for (int pi = 0; pi < 4; ++pi)
#pragma unroll
                    for (int ni = 0; ni < 4; ++ni)
                        acc[pi][ni] = __builtin_amdgcn_mfma_f32_16x16x32_f16(
                            a[pi], b[ni], acc[pi][ni], 0, 0, 0);
            }
        }
        // fold this chunk's 4 scores/row into the packed running top-2
        float knv[4];
#pragma unroll
        for (int ni = 0; ni < 4; ++ni) knv[ni] = kn[m0 + wc * 64 + ni * 16 + colk];
#pragma unroll
        for (int pi = 0; pi < 4; ++pi) {
#pragma unroll
            for (int r = 0; r < 4; ++r) {
                int si = pi * 4 + r;
#pragma unroll
                for (int ni = 0; ni < 4; ++ni) {
                    float sc = fmaf(-2.0f, acc[pi][ni][r], knv[ni]);   // single rnorm use!
                    unsigned p = (__float_as_uint(sc) & ~31u) | (unsigned)(ch * 4 + ni);
                    unsigned hi = pk1[si] > p ? pk1[si] : p;   // max
                    pk1[si] = pk1[si] < p ? pk1[si] : p;       // min
                    pk2[si] = pk2[si] < hi ? pk2[si] : hi;     // min
                }
            }
        }
    }

    // ---- once-per-block epilogue: unpack, butterfly over 16 colk lanes, LDS wc-merge ----
    __syncthreads();
    float4* red = (float4*)(void*)As;            // [128 pixels][2 waves], 4 KiB
#pragma unroll
    for (int pi = 0; pi < 4; ++pi) {
#pragma unroll
        for (int r = 0; r < 4; ++r) {
            int si = pi * 4 + r;
            int pix = wr * 64 + pi * 16 + quad * 4 + r;
            unsigned P1 = pk1[si], P2 = pk2[si];
            float s1 = __uint_as_float(P1 & ~31u);
            float s2 = __uint_as_float(P2 & ~31u);
            unsigned l1 = P1 & 31u, l2 = P2 & 31u;
            unsigned i1 = (unsigned)(yb * 1024) + (l1 >> 2) * 128 + wc * 64 + (l1 & 3) * 16 + colk;
            unsigned i2 = (unsigned)(yb * 1024) + (l2 >> 2) * 128 + wc * 64 + (l2 & 3) * 16 + colk;
#pragma unroll
            for (int mask = 1; mask < 16; mask <<= 1) {
                float t1 = __shfl_xor(s1, mask, 64);
                float t2 = __shfl_xor(s2, mask, 64);
                unsigned j1 = (unsigned)__shfl_xor((int)i1, mask, 64);
                unsigned j2 = (unsigned)__shfl_xor((int)i2, mask, 64);
                merge2(s1, i1, s2, i2, t1, j1, t2, j2);
            }
            if (colk == 0)
                red[pix * 2 + wc] = make_float4(s1, __uint_as_float(i1),
                                                s2, __uint_as_float(i2));
        }
    }
    __syncthreads();
    if (t < 128) {
        float4 e0 = red[t * 2 + 0];
        float4 e1 = red[t * 2 + 1];
        float s1 = e0.x, s2 = e0.z;
        unsigned i1 = __float_as_uint(e0.y), i2 = __float_as_uint(e0.w);
        merge2(s1, i1, s2, i2, e1.x, __float_as_uint(e1.y), e1.z, __float_as_uint(e1.w));
        best[(size_t)yb * N_ + p0 + t] =
            make_float4(s1, __uint_as_float(i1), s2, __uint_as_float(i2));
    }
}

// ---------------- kernel 5: merge 2 halves -> top-2, exact fp32 rescue + heatmap ----------------
__global__ __launch_bounds__(256) void k_heat(
    const float* __restrict__ q, const float* __restrict__ keys,
    const float* __restrict__ kn, const float* __restrict__ rnorm,
    const float4* __restrict__ best, float* __restrict__ out)
{
    int p = blockIdx.x * 256 + threadIdx.x;
    const float* qb = q + (size_t)(p / HW_) * (D_ * HW_) + (p % HW_);
    float4 e0 = best[p];
    float4 e1 = best[N_ + p];
    float s1 = e0.x, s2 = e0.z;
    unsigned i1 = __float_as_uint(e0.y), i2 = __float_as_uint(e0.w);
    merge2(s1, i1, s2, i2, e1.x, __float_as_uint(e1.y), e1.z, __float_as_uint(e1.w));
    unsigned ci[2] = { i1, i2 };

    float rn = rnorm[p];
    const float* kp[2] = { keys + (size_t)ci[0] * D_, keys + (size_t)ci[1] * D_ };
    float dot[2] = {0.f, 0.f}, hh[2] = {0.f, 0.f};
    for (int c = 0; c < D_; c += 4) {
        float qv[4];
#pragma unroll
        for (int j = 0; j < 4; ++j) qv[j] = qb[(size_t)(c + j) * HW_] * rn;  // coalesced
#pragma unroll
        for (int i = 0; i < 2; ++i) {
            float4 kv = *(const float4*)(kp[i] + c);
            dot[i] += qv[0] * kv.x + qv[1] * kv.y + qv[2] * kv.z + qv[3] * kv.w;
            float d0 = qv[0] - kv.x, d1 = qv[1] - kv.y, d2 = qv[2] - kv.z, d3 = qv[3] - kv.w;
            float e0_ = d0 * d0, e1_ = d1 * d1, e2_ = d2 * d2, e3_ = d3 * d3;
            hh[i] += e0_ * e0_ + e1_ * e1_ + e2_ * e2_ + e3_ * e3_;
        }
    }
    float sA = kn[ci[0]] - 2.0f * dot[0];
    float sB = kn[ci[1]] - 2.0f * dot[1];
    // argmin semantics: smaller exact score wins; tie -> smaller index
    bool takeB = (sB < sA) || (sB == sA && ci[1] < ci[0]);
    out[p] = takeB ? hh[1] : hh[0];
}

extern "C" void kernel_launch(void* const* d_in, const int* in_sizes, int n_in,
                              void* d_out, int out_size, void* d_ws, size_t ws_size,
                              hipStream_t stream) {
    const float* query = (const float*)d_in[0];   // (8,512,64,64) f32
    const float* keys  = (const float*)d_in[1];   // (2000,512) f32
    float* out = (float*)d_out;                   // 32768 f32

    // workspace layout (~37 MB):
    char* ws = (char*)d_ws;
    _Float16* qsw   = (_Float16*)ws;                                 // N*D fp16  = 33.5 MB
    _Float16* ksw   = (_Float16*)(ws + (size_t)N_ * D_ * 2);         // MP*D fp16 = 2 MB
    float*    rnorm = (float*)(ws + (size_t)N_ * D_ * 2 + (size_t)MP_ * D_ * 2);
    float*    kn    = rnorm + N_;
    float4*   best  = (float4*)(kn + MP_);                           // 2*N float4 = 1 MB

    k_prep<<<N_ / 64,             256, 0, stream>>>(query, rnorm, qsw);
    k_kn  <<<MP_ / 4,             256, 0, stream>>>(keys, kn);
    k_ksw <<<MP_ * D_ / 8 / 256,  256, 0, stream>>>(keys, ksw);
    k_mfma<<<dim3(N_ / 128, 2),   256, 0, stream>>>(qsw, ksw, kn, best);
    k_heat<<<N_ / 256,            256, 0, stream>>>(query, keys, kn, rnorm, best, out);
}